// Round 1
// baseline (506.802 us; speedup 1.0000x reference)
//
#include <hip/hip_runtime.h>
#include <hip/hip_bf16.h>
#include <math.h>

#define NB   64      // batch
#define D2   64      // objects per batch
#define OBJ  26      // K+2 features per object
#define NQST 11
#define HID  256
#define NOUT 28
#define NTILE 16     // p-tiles per batch (4 p's each -> M=256 pairs)

typedef __attribute__((ext_vector_type(8))) short s16x8;
typedef __attribute__((ext_vector_type(4))) float f32x4;

__device__ __forceinline__ unsigned short f2bf(float f) {
    union { float f; unsigned u; } v; v.f = f;
    unsigned r = v.u + 0x7FFFu + ((v.u >> 16) & 1u);
    return (unsigned short)(r >> 16);
}
__device__ __forceinline__ float bf2f(unsigned short h) {
    union { unsigned u; float f; } v; v.u = ((unsigned)h) << 16;
    return v.f;
}

// ---------------------------------------------------------------------------
// Kernel 1: per-batch A[q][n], B[p][n] (bf16) from the g1 decomposition.
//   A[q] = o[q] @ g1_w[0:26]
//   B[p] = o[p] @ g1_w[26:52] + qst @ g1_w[52:63] + g1_b
// ---------------------------------------------------------------------------
__global__ __launch_bounds__(256) void prep_kernel(
        const float* __restrict__ x, const float* __restrict__ qst,
        const float* __restrict__ g1_w, const float* __restrict__ g1_b,
        unsigned short* __restrict__ Abf, unsigned short* __restrict__ Bbf) {
    int b = blockIdx.x;
    int tid = threadIdx.x;
    __shared__ float o_lds[D2][OBJ];
    for (int idx = tid; idx < 24 * D2; idx += 256) {
        int c = idx >> 6, pos = idx & 63;
        o_lds[pos][c] = x[(b * 24 + c) * D2 + pos];
    }
    if (tid < D2) {
        o_lds[tid][24] = (float)(tid & 7) * (8.0f / 7.0f) - 4.0f;  // cx = coords[col]
        o_lds[tid][25] = (float)(tid >> 3) * (8.0f / 7.0f) - 4.0f; // cy = coords[row]
    }
    __syncthreads();
    int n = tid;  // 0..255
    float qpart = g1_b[n];
    for (int s = 0; s < NQST; ++s)
        qpart += qst[b * NQST + s] * g1_w[(2 * OBJ + s) * HID + n];
    for (int q0 = 0; q0 < D2; q0 += 16) {
        float accA[16], accB[16];
        #pragma unroll
        for (int i = 0; i < 16; ++i) { accA[i] = 0.f; accB[i] = 0.f; }
        for (int c = 0; c < OBJ; ++c) {
            float wA = g1_w[c * HID + n];
            float wB = g1_w[(OBJ + c) * HID + n];
            #pragma unroll
            for (int i = 0; i < 16; ++i) {
                float ov = o_lds[q0 + i][c];
                accA[i] += ov * wA;
                accB[i] += ov * wB;
            }
        }
        #pragma unroll
        for (int i = 0; i < 16; ++i) {
            int q = q0 + i;
            Abf[(b * D2 + q) * HID + n] = f2bf(accA[i]);
            Bbf[(b * D2 + q) * HID + n] = f2bf(accB[i] + qpart);
        }
    }
}

// ---------------------------------------------------------------------------
// Kernel 2: convert+transpose g2/g3/g4 weights: Wt[l][n][k] = W_l[k][n] (bf16)
// block = (l, n); thread k -> coalesced bf16 writes along k.
// ---------------------------------------------------------------------------
__global__ __launch_bounds__(256) void wconv_kernel(
        const float* __restrict__ g2_w, const float* __restrict__ g3_w,
        const float* __restrict__ g4_w, unsigned short* __restrict__ Wt) {
    int l = blockIdx.x >> 8;
    int n = blockIdx.x & 255;
    const float* W = (l == 0) ? g2_w : ((l == 1) ? g3_w : g4_w);
    int k = threadIdx.x;
    Wt[(l * HID + n) * HID + k] = f2bf(W[k * HID + n]);
}

// ---------------------------------------------------------------------------
// Kernel 3: main fused g-network. One WG = 256 pairs (4 p's x 64 q's).
// h tile 256x256 bf16 in swizzled LDS; 3 MFMA layers in-place; final
// layer reduced over pairs -> partial[b][tile][256] fp32.
// ---------------------------------------------------------------------------
__global__ __launch_bounds__(512, 2) void rn_main(
        const unsigned short* __restrict__ Abf, const unsigned short* __restrict__ Bbf,
        const unsigned short* __restrict__ Wt,
        const float* __restrict__ g2_b, const float* __restrict__ g3_b,
        const float* __restrict__ g4_b, float* __restrict__ partial) {
    // XCD-aware swizzle: 1024 WGs, 8 XCDs -> each XCD gets 8 consecutive batches
    int wg = blockIdx.x;
    int swz = (wg & 7) * 128 + (wg >> 3);
    int b = swz >> 4;
    int t = swz & 15;

    __shared__ unsigned short h_lds[256 * HID];   // 128 KiB
    __shared__ float sums_lds[8][HID];            // 8 KiB

    int tid = threadIdx.x;
    int lane = tid & 63;
    int wid = tid >> 6;

    // ---- layer 1: h1[m][k] = relu(A[q=m&63][k] + B[p=t*4+(m>>6)][k]) ----
    {
        const unsigned short* Ab = Abf + (size_t)(b * D2) * HID;
        const unsigned short* Bb = Bbf + (size_t)(b * D2 + t * 4) * HID;
        #pragma unroll
        for (int i = 0; i < 16; ++i) {
            int c = tid + i * 512;       // chunk of 8 bf16; 8192 chunks total
            int m = c >> 5;
            int k0 = (c & 31) * 8;
            int q = m & 63;
            int lp = m >> 6;
            s16x8 av = *(const s16x8*)(Ab + q * HID + k0);
            s16x8 bv = *(const s16x8*)(Bb + lp * HID + k0);
            s16x8 hv;
            #pragma unroll
            for (int j = 0; j < 8; ++j) {
                float f = bf2f((unsigned short)av[j]) + bf2f((unsigned short)bv[j]);
                f = f > 0.f ? f : 0.f;
                hv[j] = (short)f2bf(f);
            }
            int byte = (m * 512 + k0 * 2) ^ ((m & 7) << 4);
            *(s16x8*)((char*)h_lds + byte) = hv;
        }
    }
    __syncthreads();

    int wave_m = wid & 3;   // m-slice of 64 rows
    int wave_n = wid >> 2;  // n-slice of 128 cols
    int row_g = lane >> 4;  // 0..3
    int col = lane & 15;

    for (int layer = 0; layer < 3; ++layer) {
        const unsigned short* Wl = Wt + (size_t)layer * HID * HID;
        const float* bias = (layer == 0) ? g2_b : ((layer == 1) ? g3_b : g4_b);

        f32x4 acc[4][8];
        #pragma unroll
        for (int mf = 0; mf < 4; ++mf)
            #pragma unroll
            for (int nf = 0; nf < 8; ++nf)
                acc[mf][nf] = (f32x4){0.f, 0.f, 0.f, 0.f};

        for (int ks = 0; ks < 8; ++ks) {
            int kb = ks * 32 + row_g * 8;   // this lane's k-base within K
            s16x8 bfr[8];
            #pragma unroll
            for (int nf = 0; nf < 8; ++nf) {
                int n = wave_n * 128 + nf * 16 + col;
                bfr[nf] = *(const s16x8*)(Wl + n * HID + kb);
            }
            s16x8 afr[4];
            #pragma unroll
            for (int mf = 0; mf < 4; ++mf) {
                int m = wave_m * 64 + mf * 16 + col;
                int byte = (m * 512 + kb * 2) ^ ((m & 7) << 4);
                afr[mf] = *(const s16x8*)((const char*)h_lds + byte);
            }
            #pragma unroll
            for (int mf = 0; mf < 4; ++mf)
                #pragma unroll
                for (int nf = 0; nf < 8; ++nf)
                    acc[mf][nf] = __builtin_amdgcn_mfma_f32_16x16x32_bf16(
                        afr[mf], bfr[nf], acc[mf][nf], 0, 0, 0);
        }
        __syncthreads();   // all reads of h_lds done before overwrite / epilogue

        if (layer < 2) {
            #pragma unroll
            for (int nf = 0; nf < 8; ++nf) {
                float bv = bias[wave_n * 128 + nf * 16 + col];
                #pragma unroll
                for (int mf = 0; mf < 4; ++mf) {
                    #pragma unroll
                    for (int r = 0; r < 4; ++r) {
                        float v = acc[mf][nf][r] + bv;
                        v = v > 0.f ? v : 0.f;
                        int m = wave_m * 64 + mf * 16 + row_g * 4 + r;
                        int n = wave_n * 128 + nf * 16 + col;
                        int byte = (m * 512 + n * 2) ^ ((m & 7) << 4);
                        *(unsigned short*)((char*)h_lds + byte) = f2bf(v);
                    }
                }
            }
            __syncthreads();
        } else {
            // final layer: relu + sum over the 256 pairs of this tile
            #pragma unroll
            for (int nf = 0; nf < 8; ++nf) {
                float bv = bias[wave_n * 128 + nf * 16 + col];
                float s = 0.f;
                #pragma unroll
                for (int mf = 0; mf < 4; ++mf)
                    #pragma unroll
                    for (int r = 0; r < 4; ++r) {
                        float v = acc[mf][nf][r] + bv;
                        s += v > 0.f ? v : 0.f;
                    }
                s += __shfl_xor(s, 16);
                s += __shfl_xor(s, 32);
                if (row_g == 0)
                    sums_lds[wid][wave_n * 128 + nf * 16 + col] = s;
            }
            __syncthreads();
            for (int n = tid; n < HID; n += 512) {
                int wn = n >> 7;
                float s = sums_lds[wn * 4 + 0][n] + sums_lds[wn * 4 + 1][n]
                        + sums_lds[wn * 4 + 2][n] + sums_lds[wn * 4 + 3][n];
                partial[(size_t)(b * NTILE + t) * HID + n] = s;
            }
        }
    }
}

// ---------------------------------------------------------------------------
// Kernel 4: per-batch reduce over tiles + f-network (fp32) + log_softmax
// ---------------------------------------------------------------------------
__global__ __launch_bounds__(256) void fuse_kernel(
        const float* __restrict__ partial,
        const float* __restrict__ f1_w, const float* __restrict__ f1_b,
        const float* __restrict__ f2_w, const float* __restrict__ f2_b,
        const float* __restrict__ f3_w, const float* __restrict__ f3_b,
        float* __restrict__ out) {
    int b = blockIdx.x;
    int tid = threadIdx.x;
    __shared__ float xg[HID];
    __shared__ float h1[HID];
    __shared__ float h2[HID];
    __shared__ float lred[NOUT];
    __shared__ float lse;

    float s = 0.f;
    for (int t = 0; t < NTILE; ++t)
        s += partial[(size_t)(b * NTILE + t) * HID + tid];
    xg[tid] = s;
    __syncthreads();

    float a1 = f1_b[tid];
    for (int k = 0; k < HID; ++k)
        a1 += xg[k] * f1_w[k * HID + tid];
    h1[tid] = a1 > 0.f ? a1 : 0.f;
    __syncthreads();

    float a2 = f2_b[tid];
    for (int k = 0; k < HID; ++k)
        a2 += h1[k] * f2_w[k * HID + tid];
    h2[tid] = a2 > 0.f ? a2 : 0.f;
    __syncthreads();

    float logit = 0.f;
    if (tid < NOUT) {
        logit = f3_b[tid];
        for (int k = 0; k < HID; ++k)
            logit += h2[k] * f3_w[k * NOUT + tid];
        lred[tid] = logit;
    }
    __syncthreads();
    if (tid == 0) {
        float mx = lred[0];
        for (int j = 1; j < NOUT; ++j) mx = fmaxf(mx, lred[j]);
        float se = 0.f;
        for (int j = 0; j < NOUT; ++j) se += expf(lred[j] - mx);
        lse = mx + logf(se);
    }
    __syncthreads();
    if (tid < NOUT)
        out[b * NOUT + tid] = logit - lse;
}

// ---------------------------------------------------------------------------
extern "C" void kernel_launch(void* const* d_in, const int* in_sizes, int n_in,
                              void* d_out, int out_size, void* d_ws, size_t ws_size,
                              hipStream_t stream) {
    const float* x    = (const float*)d_in[0];
    const float* qst  = (const float*)d_in[1];
    const float* g1_w = (const float*)d_in[2];
    const float* g1_b = (const float*)d_in[3];
    const float* g2_w = (const float*)d_in[4];
    const float* g2_b = (const float*)d_in[5];
    const float* g3_w = (const float*)d_in[6];
    const float* g3_b = (const float*)d_in[7];
    const float* g4_w = (const float*)d_in[8];
    const float* g4_b = (const float*)d_in[9];
    const float* f1_w = (const float*)d_in[10];
    const float* f1_b = (const float*)d_in[11];
    const float* f2_w = (const float*)d_in[12];
    const float* f2_b = (const float*)d_in[13];
    const float* f3_w = (const float*)d_in[14];
    const float* f3_b = (const float*)d_in[15];
    float* out = (float*)d_out;

    char* ws = (char*)d_ws;
    unsigned short* Abf = (unsigned short*)ws;                          // 2 MiB
    unsigned short* Bbf = (unsigned short*)(ws + (2u << 20));           // 2 MiB
    unsigned short* Wt  = (unsigned short*)(ws + (4u << 20));           // 384 KiB
    float* partial      = (float*)(ws + (4u << 20) + (384u << 10));     // 1 MiB

    prep_kernel<<<NB, 256, 0, stream>>>(x, qst, g1_w, g1_b, Abf, Bbf);
    wconv_kernel<<<3 * 256, 256, 0, stream>>>(g2_w, g3_w, g4_w, Wt);
    rn_main<<<NB * NTILE, 512, 0, stream>>>(Abf, Bbf, Wt, g2_b, g3_b, g4_b, partial);
    fuse_kernel<<<NB, 256, 0, stream>>>(partial, f1_w, f1_b, f2_w, f2_b, f3_w, f3_b, out);
}

// Round 2
// 449.873 us; speedup vs baseline: 1.1265x; 1.1265x over previous
//
#include <hip/hip_runtime.h>
#include <hip/hip_bf16.h>
#include <math.h>

#define NB   64      // batch
#define D2   64      // objects per batch
#define OBJ  26      // K+2 features per object
#define NQST 11
#define HID  256
#define NOUT 28
#define NTILE 32     // p-tiles per batch (2 p's each -> M=128 pairs)
#define MPW  128     // pairs per workgroup

typedef __attribute__((ext_vector_type(8))) short s16x8;
typedef __attribute__((ext_vector_type(4))) float f32x4;

__device__ __forceinline__ unsigned short f2bf(float f) {
    union { float f; unsigned u; } v; v.f = f;
    unsigned r = v.u + 0x7FFFu + ((v.u >> 16) & 1u);
    return (unsigned short)(r >> 16);
}
__device__ __forceinline__ float bf2f(unsigned short h) {
    union { unsigned u; float f; } v; v.u = ((unsigned)h) << 16;
    return v.f;
}

// ---------------------------------------------------------------------------
// Kernel 1: per-batch A[q][n], B[p][n] (bf16) from the g1 decomposition.
//   A[q] = o[q] @ g1_w[0:26]
//   B[p] = o[p] @ g1_w[26:52] + qst @ g1_w[52:63] + g1_b
// ---------------------------------------------------------------------------
__global__ __launch_bounds__(256) void prep_kernel(
        const float* __restrict__ x, const float* __restrict__ qst,
        const float* __restrict__ g1_w, const float* __restrict__ g1_b,
        unsigned short* __restrict__ Abf, unsigned short* __restrict__ Bbf) {
    int b = blockIdx.x;
    int tid = threadIdx.x;
    __shared__ float o_lds[D2][OBJ];
    for (int idx = tid; idx < 24 * D2; idx += 256) {
        int c = idx >> 6, pos = idx & 63;
        o_lds[pos][c] = x[(b * 24 + c) * D2 + pos];
    }
    if (tid < D2) {
        o_lds[tid][24] = (float)(tid & 7) * (8.0f / 7.0f) - 4.0f;  // cx = coords[col]
        o_lds[tid][25] = (float)(tid >> 3) * (8.0f / 7.0f) - 4.0f; // cy = coords[row]
    }
    __syncthreads();
    int n = tid;  // 0..255
    float qpart = g1_b[n];
    for (int s = 0; s < NQST; ++s)
        qpart += qst[b * NQST + s] * g1_w[(2 * OBJ + s) * HID + n];
    for (int q0 = 0; q0 < D2; q0 += 16) {
        float accA[16], accB[16];
        #pragma unroll
        for (int i = 0; i < 16; ++i) { accA[i] = 0.f; accB[i] = 0.f; }
        for (int c = 0; c < OBJ; ++c) {
            float wA = g1_w[c * HID + n];
            float wB = g1_w[(OBJ + c) * HID + n];
            #pragma unroll
            for (int i = 0; i < 16; ++i) {
                float ov = o_lds[q0 + i][c];
                accA[i] += ov * wA;
                accB[i] += ov * wB;
            }
        }
        #pragma unroll
        for (int i = 0; i < 16; ++i) {
            int q = q0 + i;
            Abf[(b * D2 + q) * HID + n] = f2bf(accA[i]);
            Bbf[(b * D2 + q) * HID + n] = f2bf(accB[i] + qpart);
        }
    }
}

// ---------------------------------------------------------------------------
// Kernel 2: convert+transpose g2/g3/g4 weights: Wt[l][n][k] = W_l[k][n] (bf16)
// ---------------------------------------------------------------------------
__global__ __launch_bounds__(256) void wconv_kernel(
        const float* __restrict__ g2_w, const float* __restrict__ g3_w,
        const float* __restrict__ g4_w, unsigned short* __restrict__ Wt) {
    int l = blockIdx.x >> 8;
    int n = blockIdx.x & 255;
    const float* W = (l == 0) ? g2_w : ((l == 1) ? g3_w : g4_w);
    int k = threadIdx.x;
    Wt[(l * HID + n) * HID + k] = f2bf(W[k * HID + n]);
}

// ---------------------------------------------------------------------------
// Kernel 3: main fused g-network. One WG = 128 pairs (2 p's x 64 q's).
// h tile 128x256 bf16 in swizzled LDS (64 KiB); 3 MFMA layers in-place;
// final layer reduced over pairs -> partial[b][tile][256] fp32.
// 8 waves as 2 (m) x 4 (n); per-wave 64x64 output -> acc = 64 VGPRs (no spill).
// 2 blocks/CU co-resident (73.5 KiB LDS, 128 VGPRs).
// ---------------------------------------------------------------------------
__global__ __launch_bounds__(512, 4) void rn_main(
        const unsigned short* __restrict__ Abf, const unsigned short* __restrict__ Bbf,
        const unsigned short* __restrict__ Wt,
        const float* __restrict__ g2_b, const float* __restrict__ g3_b,
        const float* __restrict__ g4_b, float* __restrict__ partial) {
    // XCD-aware swizzle: 2048 WGs, 8 XCDs (2048 % 8 == 0 -> bijective)
    int wg = blockIdx.x;
    int swz = (wg & 7) * 256 + (wg >> 3);
    int b = swz >> 5;
    int t = swz & 31;

    __shared__ unsigned short h_lds[MPW * HID];   // 64 KiB
    __shared__ float sums_lds[8][HID];            // 8 KiB

    int tid = threadIdx.x;
    int lane = tid & 63;
    int wid = tid >> 6;

    // ---- layer 1: h1[m][k] = relu(A[q=m&63][k] + B[p=t*2+(m>>6)][k]) ----
    {
        const unsigned short* Ab = Abf + (size_t)(b * D2) * HID;
        const unsigned short* Bb = Bbf + (size_t)(b * D2 + t * 2) * HID;
        #pragma unroll
        for (int i = 0; i < 8; ++i) {
            int c = tid + i * 512;       // chunk of 8 bf16; 4096 chunks total
            int m = c >> 5;
            int k0 = (c & 31) * 8;
            int q = m & 63;
            int lp = m >> 6;
            s16x8 av = *(const s16x8*)(Ab + q * HID + k0);
            s16x8 bv = *(const s16x8*)(Bb + lp * HID + k0);
            s16x8 hv;
            #pragma unroll
            for (int j = 0; j < 8; ++j) {
                float f = bf2f((unsigned short)av[j]) + bf2f((unsigned short)bv[j]);
                f = f > 0.f ? f : 0.f;
                hv[j] = (short)f2bf(f);
            }
            int byte = (m * 512 + k0 * 2) ^ ((m & 7) << 4);
            *(s16x8*)((char*)h_lds + byte) = hv;
        }
    }
    __syncthreads();

    int wave_m = wid & 1;   // m-slice of 64 rows
    int wave_n = wid >> 1;  // n-slice of 64 cols
    int row_g = lane >> 4;  // 0..3
    int col = lane & 15;

    for (int layer = 0; layer < 3; ++layer) {
        const unsigned short* Wl = Wt + (size_t)layer * HID * HID;
        const float* bias = (layer == 0) ? g2_b : ((layer == 1) ? g3_b : g4_b);

        f32x4 acc[4][4];
        #pragma unroll
        for (int mf = 0; mf < 4; ++mf)
            #pragma unroll
            for (int nf = 0; nf < 4; ++nf)
                acc[mf][nf] = (f32x4){0.f, 0.f, 0.f, 0.f};

        for (int ks = 0; ks < 8; ++ks) {
            int kb = ks * 32 + row_g * 8;   // this lane's k-base within K
            s16x8 bfr[4];
            #pragma unroll
            for (int nf = 0; nf < 4; ++nf) {
                int n = wave_n * 64 + nf * 16 + col;
                bfr[nf] = *(const s16x8*)(Wl + n * HID + kb);
            }
            s16x8 afr[4];
            #pragma unroll
            for (int mf = 0; mf < 4; ++mf) {
                int m = wave_m * 64 + mf * 16 + col;
                int byte = (m * 512 + kb * 2) ^ ((m & 7) << 4);
                afr[mf] = *(const s16x8*)((const char*)h_lds + byte);
            }
            #pragma unroll
            for (int mf = 0; mf < 4; ++mf)
                #pragma unroll
                for (int nf = 0; nf < 4; ++nf)
                    acc[mf][nf] = __builtin_amdgcn_mfma_f32_16x16x32_bf16(
                        afr[mf], bfr[nf], acc[mf][nf], 0, 0, 0);
        }
        __syncthreads();   // all reads of h_lds done before overwrite / epilogue

        if (layer < 2) {
            #pragma unroll
            for (int nf = 0; nf < 4; ++nf) {
                float bv = bias[wave_n * 64 + nf * 16 + col];
                #pragma unroll
                for (int mf = 0; mf < 4; ++mf) {
                    #pragma unroll
                    for (int r = 0; r < 4; ++r) {
                        float v = acc[mf][nf][r] + bv;
                        v = v > 0.f ? v : 0.f;
                        int m = wave_m * 64 + mf * 16 + row_g * 4 + r;
                        int n = wave_n * 64 + nf * 16 + col;
                        int byte = (m * 512 + n * 2) ^ ((m & 7) << 4);
                        *(unsigned short*)((char*)h_lds + byte) = f2bf(v);
                    }
                }
            }
            __syncthreads();
        } else {
            // final layer: relu + sum over the 128 pairs of this tile
            #pragma unroll
            for (int nf = 0; nf < 4; ++nf) {
                float bv = bias[wave_n * 64 + nf * 16 + col];
                float s = 0.f;
                #pragma unroll
                for (int mf = 0; mf < 4; ++mf)
                    #pragma unroll
                    for (int r = 0; r < 4; ++r) {
                        float v = acc[mf][nf][r] + bv;
                        s += v > 0.f ? v : 0.f;
                    }
                s += __shfl_xor(s, 16);
                s += __shfl_xor(s, 32);
                if (row_g == 0)
                    sums_lds[wid][wave_n * 64 + nf * 16 + col] = s;
            }
            __syncthreads();
            if (tid < HID) {
                int n = tid;
                int wn = n >> 6;            // which wave_n column group
                float s = sums_lds[wn * 2 + 0][n] + sums_lds[wn * 2 + 1][n];
                partial[(size_t)(b * NTILE + t) * HID + n] = s;
            }
        }
    }
}

// ---------------------------------------------------------------------------
// Kernel 4: per-batch reduce over tiles + f-network (fp32) + log_softmax
// ---------------------------------------------------------------------------
__global__ __launch_bounds__(256) void fuse_kernel(
        const float* __restrict__ partial,
        const float* __restrict__ f1_w, const float* __restrict__ f1_b,
        const float* __restrict__ f2_w, const float* __restrict__ f2_b,
        const float* __restrict__ f3_w, const float* __restrict__ f3_b,
        float* __restrict__ out) {
    int b = blockIdx.x;
    int tid = threadIdx.x;
    __shared__ float xg[HID];
    __shared__ float h1[HID];
    __shared__ float h2[HID];
    __shared__ float lred[NOUT];
    __shared__ float lse;

    float s = 0.f;
    for (int t = 0; t < NTILE; ++t)
        s += partial[(size_t)(b * NTILE + t) * HID + tid];
    xg[tid] = s;
    __syncthreads();

    float a1 = f1_b[tid];
    for (int k = 0; k < HID; ++k)
        a1 += xg[k] * f1_w[k * HID + tid];
    h1[tid] = a1 > 0.f ? a1 : 0.f;
    __syncthreads();

    float a2 = f2_b[tid];
    for (int k = 0; k < HID; ++k)
        a2 += h1[k] * f2_w[k * HID + tid];
    h2[tid] = a2 > 0.f ? a2 : 0.f;
    __syncthreads();

    float logit = 0.f;
    if (tid < NOUT) {
        logit = f3_b[tid];
        for (int k = 0; k < HID; ++k)
            logit += h2[k] * f3_w[k * NOUT + tid];
        lred[tid] = logit;
    }
    __syncthreads();
    if (tid == 0) {
        float mx = lred[0];
        for (int j = 1; j < NOUT; ++j) mx = fmaxf(mx, lred[j]);
        float se = 0.f;
        for (int j = 0; j < NOUT; ++j) se += expf(lred[j] - mx);
        lse = mx + logf(se);
    }
    __syncthreads();
    if (tid < NOUT)
        out[b * NOUT + tid] = logit - lse;
}

// ---------------------------------------------------------------------------
extern "C" void kernel_launch(void* const* d_in, const int* in_sizes, int n_in,
                              void* d_out, int out_size, void* d_ws, size_t ws_size,
                              hipStream_t stream) {
    const float* x    = (const float*)d_in[0];
    const float* qst  = (const float*)d_in[1];
    const float* g1_w = (const float*)d_in[2];
    const float* g1_b = (const float*)d_in[3];
    const float* g2_w = (const float*)d_in[4];
    const float* g2_b = (const float*)d_in[5];
    const float* g3_w = (const float*)d_in[6];
    const float* g3_b = (const float*)d_in[7];
    const float* g4_w = (const float*)d_in[8];
    const float* g4_b = (const float*)d_in[9];
    const float* f1_w = (const float*)d_in[10];
    const float* f1_b = (const float*)d_in[11];
    const float* f2_w = (const float*)d_in[12];
    const float* f2_b = (const float*)d_in[13];
    const float* f3_w = (const float*)d_in[14];
    const float* f3_b = (const float*)d_in[15];
    float* out = (float*)d_out;

    char* ws = (char*)d_ws;
    unsigned short* Abf = (unsigned short*)ws;                          // 2 MiB
    unsigned short* Bbf = (unsigned short*)(ws + (2u << 20));           // 2 MiB
    unsigned short* Wt  = (unsigned short*)(ws + (4u << 20));           // 384 KiB
    float* partial      = (float*)(ws + (4u << 20) + (512u << 10));     // 2 MiB

    prep_kernel<<<NB, 256, 0, stream>>>(x, qst, g1_w, g1_b, Abf, Bbf);
    wconv_kernel<<<3 * 256, 256, 0, stream>>>(g2_w, g3_w, g4_w, Wt);
    rn_main<<<NB * NTILE, 512, 0, stream>>>(Abf, Bbf, Wt, g2_b, g3_b, g4_b, partial);
    fuse_kernel<<<NB, 256, 0, stream>>>(partial, f1_w, f1_b, f2_w, f2_b, f3_w, f3_b, out);
}

// Round 3
// 238.984 us; speedup vs baseline: 2.1206x; 1.8824x over previous
//
#include <hip/hip_runtime.h>
#include <hip/hip_bf16.h>
#include <math.h>

#define NB   64      // batch
#define D2   64      // objects per batch
#define OBJ  26      // K+2 features per object
#define NQST 11
#define HID  256
#define NOUT 28
#define NTILE 32     // p-tiles per batch (2 p's each, processed sequentially)

typedef __attribute__((ext_vector_type(8))) short s16x8;
typedef __attribute__((ext_vector_type(4))) float f32x4;

__device__ __forceinline__ unsigned short f2bf(float f) {
    union { float f; unsigned u; } v; v.f = f;
    unsigned r = v.u + 0x7FFFu + ((v.u >> 16) & 1u);
    return (unsigned short)(r >> 16);
}
__device__ __forceinline__ float bf2f(unsigned short h) {
    union { unsigned u; float f; } v; v.u = ((unsigned)h) << 16;
    return v.f;
}

// ---------------------------------------------------------------------------
// Kernel 1: per-batch A[q][n], B[p][n] (bf16) from the g1 decomposition.
//   A[q] = o[q] @ g1_w[0:26]
//   B[p] = o[p] @ g1_w[26:52] + qst @ g1_w[52:63] + g1_b
// ---------------------------------------------------------------------------
__global__ __launch_bounds__(256) void prep_kernel(
        const float* __restrict__ x, const float* __restrict__ qst,
        const float* __restrict__ g1_w, const float* __restrict__ g1_b,
        unsigned short* __restrict__ Abf, unsigned short* __restrict__ Bbf) {
    int b = blockIdx.x;
    int tid = threadIdx.x;
    __shared__ float o_lds[D2][OBJ];
    for (int idx = tid; idx < 24 * D2; idx += 256) {
        int c = idx >> 6, pos = idx & 63;
        o_lds[pos][c] = x[(b * 24 + c) * D2 + pos];
    }
    if (tid < D2) {
        o_lds[tid][24] = (float)(tid & 7) * (8.0f / 7.0f) - 4.0f;  // cx = coords[col]
        o_lds[tid][25] = (float)(tid >> 3) * (8.0f / 7.0f) - 4.0f; // cy = coords[row]
    }
    __syncthreads();
    int n = tid;  // 0..255
    float qpart = g1_b[n];
    for (int s = 0; s < NQST; ++s)
        qpart += qst[b * NQST + s] * g1_w[(2 * OBJ + s) * HID + n];
    for (int q0 = 0; q0 < D2; q0 += 16) {
        float accA[16], accB[16];
        #pragma unroll
        for (int i = 0; i < 16; ++i) { accA[i] = 0.f; accB[i] = 0.f; }
        for (int c = 0; c < OBJ; ++c) {
            float wA = g1_w[c * HID + n];
            float wB = g1_w[(OBJ + c) * HID + n];
            #pragma unroll
            for (int i = 0; i < 16; ++i) {
                float ov = o_lds[q0 + i][c];
                accA[i] += ov * wA;
                accB[i] += ov * wB;
            }
        }
        #pragma unroll
        for (int i = 0; i < 16; ++i) {
            int q = q0 + i;
            Abf[(b * D2 + q) * HID + n] = f2bf(accA[i]);
            Bbf[(b * D2 + q) * HID + n] = f2bf(accB[i] + qpart);
        }
    }
}

// ---------------------------------------------------------------------------
// Kernel 2: convert+transpose g2/g3/g4 weights: Wt[l][n][k] = W_l[k][n] (bf16)
// ---------------------------------------------------------------------------
__global__ __launch_bounds__(256) void wconv_kernel(
        const float* __restrict__ g2_w, const float* __restrict__ g3_w,
        const float* __restrict__ g4_w, unsigned short* __restrict__ Wt) {
    int l = blockIdx.x >> 8;
    int n = blockIdx.x & 255;
    const float* W = (l == 0) ? g2_w : ((l == 1) ? g3_w : g4_w);
    int k = threadIdx.x;
    Wt[(l * HID + n) * HID + k] = f2bf(W[k * HID + n]);
}

// ---------------------------------------------------------------------------
// Kernel 3: main fused g-network. One WG = p-pair {2t, 2t+1}, each processed
// as an M=64 tile (64 q-pairs) sequentially, accumulating the pair-sum.
// 8 waves as 1(m) x 8(n): per-wave 64x32 output -> acc[4][2] = 32 VGPRs.
// h tile 64x256 bf16, double-buffered swizzled LDS (2 x 32 KiB); one barrier
// per layer. Total register demand ~80 << 128 cap (unified VGPR+AGPR file:
// launch_bounds(512,4) caps combined budget at 128 — round 2 spilled because
// acc alone ate 64 and frags overflowed).
// ---------------------------------------------------------------------------
__global__ __launch_bounds__(512, 4) void rn_main(
        const unsigned short* __restrict__ Abf, const unsigned short* __restrict__ Bbf,
        const unsigned short* __restrict__ Wt,
        const float* __restrict__ g2_b, const float* __restrict__ g3_b,
        const float* __restrict__ g4_b, float* __restrict__ partial) {
    // XCD-aware swizzle: 2048 WGs, 8 XCDs (2048 % 8 == 0 -> bijective)
    int wg = blockIdx.x;
    int swz = (wg & 7) * 256 + (wg >> 3);
    int b = swz >> 5;
    int t = swz & 31;

    __shared__ unsigned short h_lds[2][D2 * HID];   // 2 x 32 KiB

    int tid = threadIdx.x;
    int lane = tid & 63;
    int wid = tid >> 6;
    int row_g = lane >> 4;  // 0..3
    int col = lane & 15;

    const unsigned short* Ab = Abf + (size_t)(b * D2) * HID;

    float pacc[2] = {0.f, 0.f};   // accumulated pair-sums for this lane's 2 n's

    for (int pp = 0; pp < 2; ++pp) {
        const unsigned short* Bb = Bbf + (size_t)(b * D2 + t * 2 + pp) * HID;

        // ---- layer 1: h1[m][k] = relu(A[q=m][k] + B[p][k]) into buf 0 ----
        #pragma unroll
        for (int i = 0; i < 4; ++i) {
            int c = tid + i * 512;       // 2048 chunks of 8 bf16
            int m = c >> 5;              // 0..63
            int k0 = (c & 31) * 8;
            s16x8 av = *(const s16x8*)(Ab + m * HID + k0);
            s16x8 bv = *(const s16x8*)(Bb + k0);
            s16x8 hv;
            #pragma unroll
            for (int j = 0; j < 8; ++j) {
                float f = bf2f((unsigned short)av[j]) + bf2f((unsigned short)bv[j]);
                f = f > 0.f ? f : 0.f;
                hv[j] = (short)f2bf(f);
            }
            int byte = (m * 512 + k0 * 2) ^ ((m & 7) << 4);
            *(s16x8*)((char*)h_lds[0] + byte) = hv;
        }
        __syncthreads();

        int cur = 0;
        for (int layer = 0; layer < 3; ++layer) {
            const unsigned short* Wl = Wt + (size_t)layer * HID * HID;
            const float* bias = (layer == 0) ? g2_b : ((layer == 1) ? g3_b : g4_b);

            f32x4 acc[4][2];
            #pragma unroll
            for (int mf = 0; mf < 4; ++mf)
                #pragma unroll
                for (int nf = 0; nf < 2; ++nf)
                    acc[mf][nf] = (f32x4){0.f, 0.f, 0.f, 0.f};

            #pragma unroll 2
            for (int ks = 0; ks < 8; ++ks) {
                int kb = ks * 32 + row_g * 8;   // this lane's k-base
                s16x8 bfr[2];
                #pragma unroll
                for (int nf = 0; nf < 2; ++nf) {
                    int n = wid * 32 + nf * 16 + col;
                    bfr[nf] = *(const s16x8*)(Wl + n * HID + kb);
                }
                s16x8 afr[4];
                #pragma unroll
                for (int mf = 0; mf < 4; ++mf) {
                    int m = mf * 16 + col;
                    int byte = (m * 512 + kb * 2) ^ ((m & 7) << 4);
                    afr[mf] = *(const s16x8*)((const char*)h_lds[cur] + byte);
                }
                #pragma unroll
                for (int mf = 0; mf < 4; ++mf)
                    #pragma unroll
                    for (int nf = 0; nf < 2; ++nf)
                        acc[mf][nf] = __builtin_amdgcn_mfma_f32_16x16x32_bf16(
                            afr[mf], bfr[nf], acc[mf][nf], 0, 0, 0);
            }

            if (layer < 2) {
                int nxt = cur ^ 1;
                #pragma unroll
                for (int nf = 0; nf < 2; ++nf) {
                    int n = wid * 32 + nf * 16 + col;
                    float bv = bias[n];
                    #pragma unroll
                    for (int mf = 0; mf < 4; ++mf)
                        #pragma unroll
                        for (int r = 0; r < 4; ++r) {
                            int m = mf * 16 + row_g * 4 + r;
                            float v = acc[mf][nf][r] + bv;
                            v = v > 0.f ? v : 0.f;
                            int byte = (m * 512 + n * 2) ^ ((m & 7) << 4);
                            *(unsigned short*)((char*)h_lds[nxt] + byte) = f2bf(v);
                        }
                }
                __syncthreads();   // nxt fully written (cur reads all pre-done)
                cur = nxt;
            } else {
                // final layer: relu + sum over this tile's 64 pairs
                #pragma unroll
                for (int nf = 0; nf < 2; ++nf) {
                    float bv = bias[wid * 32 + nf * 16 + col];
                    float s = 0.f;
                    #pragma unroll
                    for (int mf = 0; mf < 4; ++mf)
                        #pragma unroll
                        for (int r = 0; r < 4; ++r) {
                            float v = acc[mf][nf][r] + bv;
                            s += v > 0.f ? v : 0.f;
                        }
                    s += __shfl_xor(s, 16);
                    s += __shfl_xor(s, 32);
                    pacc[nf] += s;
                }
                __syncthreads();   // all reads of buf0 done before re-staging
            }
        }
    }

    if (row_g == 0) {
        #pragma unroll
        for (int nf = 0; nf < 2; ++nf)
            partial[(size_t)(b * NTILE + t) * HID + wid * 32 + nf * 16 + col]
                = pacc[nf];
    }
}

// ---------------------------------------------------------------------------
// Kernel 4: per-batch reduce over tiles + f-network (fp32) + log_softmax
// ---------------------------------------------------------------------------
__global__ __launch_bounds__(256) void fuse_kernel(
        const float* __restrict__ partial,
        const float* __restrict__ f1_w, const float* __restrict__ f1_b,
        const float* __restrict__ f2_w, const float* __restrict__ f2_b,
        const float* __restrict__ f3_w, const float* __restrict__ f3_b,
        float* __restrict__ out) {
    int b = blockIdx.x;
    int tid = threadIdx.x;
    __shared__ float xg[HID];
    __shared__ float h1[HID];
    __shared__ float h2[HID];
    __shared__ float lred[NOUT];
    __shared__ float lse;

    float s = 0.f;
    for (int t = 0; t < NTILE; ++t)
        s += partial[(size_t)(b * NTILE + t) * HID + tid];
    xg[tid] = s;
    __syncthreads();

    float a1 = f1_b[tid];
    for (int k = 0; k < HID; ++k)
        a1 += xg[k] * f1_w[k * HID + tid];
    h1[tid] = a1 > 0.f ? a1 : 0.f;
    __syncthreads();

    float a2 = f2_b[tid];
    for (int k = 0; k < HID; ++k)
        a2 += h1[k] * f2_w[k * HID + tid];
    h2[tid] = a2 > 0.f ? a2 : 0.f;
    __syncthreads();

    float logit = 0.f;
    if (tid < NOUT) {
        logit = f3_b[tid];
        for (int k = 0; k < HID; ++k)
            logit += h2[k] * f3_w[k * NOUT + tid];
        lred[tid] = logit;
    }
    __syncthreads();
    if (tid == 0) {
        float mx = lred[0];
        for (int j = 1; j < NOUT; ++j) mx = fmaxf(mx, lred[j]);
        float se = 0.f;
        for (int j = 0; j < NOUT; ++j) se += expf(lred[j] - mx);
        lse = mx + logf(se);
    }
    __syncthreads();
    if (tid < NOUT)
        out[b * NOUT + tid] = logit - lse;
}

// ---------------------------------------------------------------------------
extern "C" void kernel_launch(void* const* d_in, const int* in_sizes, int n_in,
                              void* d_out, int out_size, void* d_ws, size_t ws_size,
                              hipStream_t stream) {
    const float* x    = (const float*)d_in[0];
    const float* qst  = (const float*)d_in[1];
    const float* g1_w = (const float*)d_in[2];
    const float* g1_b = (const float*)d_in[3];
    const float* g2_w = (const float*)d_in[4];
    const float* g2_b = (const float*)d_in[5];
    const float* g3_w = (const float*)d_in[6];
    const float* g3_b = (const float*)d_in[7];
    const float* g4_w = (const float*)d_in[8];
    const float* g4_b = (const float*)d_in[9];
    const float* f1_w = (const float*)d_in[10];
    const float* f1_b = (const float*)d_in[11];
    const float* f2_w = (const float*)d_in[12];
    const float* f2_b = (const float*)d_in[13];
    const float* f3_w = (const float*)d_in[14];
    const float* f3_b = (const float*)d_in[15];
    float* out = (float*)d_out;

    char* ws = (char*)d_ws;
    unsigned short* Abf = (unsigned short*)ws;                          // 2 MiB
    unsigned short* Bbf = (unsigned short*)(ws + (2u << 20));           // 2 MiB
    unsigned short* Wt  = (unsigned short*)(ws + (4u << 20));           // 384 KiB
    float* partial      = (float*)(ws + (4u << 20) + (512u << 10));     // 2 MiB

    prep_kernel<<<NB, 256, 0, stream>>>(x, qst, g1_w, g1_b, Abf, Bbf);
    wconv_kernel<<<3 * 256, 256, 0, stream>>>(g2_w, g3_w, g4_w, Wt);
    rn_main<<<NB * NTILE, 512, 0, stream>>>(Abf, Bbf, Wt, g2_b, g3_b, g4_b, partial);
    fuse_kernel<<<NB, 256, 0, stream>>>(partial, f1_w, f1_b, f2_w, f2_b, f3_w, f3_b, out);
}